// Round 2
// baseline (215.445 us; speedup 1.0000x reference)
//
#include <hip/hip_runtime.h>
#include <hip/hip_bf16.h>
#include <stdint.h>

// Problem constants (fixed by the reference setup_inputs).
#define N_X 4096
#define M_P 8192
#define D_K 512

// GEMM tile config — m97-verified structure: 128x128 tile, BK=32, 4 waves,
// 16x16x32 bf16 MFMA, global_load_lds width=16, single barrier per K-step.
#define BM 128
#define BN 128
#define BK 32
#define NKT (D_K / BK) // 16 K-steps

typedef __attribute__((ext_vector_type(8))) short bf16x8; // 8 bf16 in 4 VGPRs
typedef __attribute__((ext_vector_type(4))) float f32x4;  // MFMA accumulator

// RNE float -> bf16 (bit math; NaN edge irrelevant for this data).
__device__ __forceinline__ unsigned short f2bf(float f) {
    union { float f; unsigned u; } c; c.f = f;
    unsigned u = c.u;
    return (unsigned short)((u + 0x7FFFu + ((u >> 16) & 1u)) >> 16);
}

// Async global->LDS, 16B per lane. LDS dest is wave-uniform base + lane*16.
__device__ __forceinline__ void gload_lds16(const void* g, void* l) {
    __builtin_amdgcn_global_load_lds(
        (const __attribute__((address_space(1))) void*)g,
        (__attribute__((address_space(3))) void*)l,
        16, 0, 0);
}

// ---------------------------------------------------------------------------
// Prep: one wave per row — f32 row norm + bf16 copy. Covers x (rows [0,N))
// then patterns (rows [N, N+M)) in a single launch.
// ---------------------------------------------------------------------------
__global__ void prep_rows(const float* __restrict__ x,
                          const float* __restrict__ pat,
                          unsigned short* __restrict__ xb,
                          unsigned short* __restrict__ pb,
                          float* __restrict__ x2, float* __restrict__ p2) {
    int gw   = (int)((blockIdx.x * blockDim.x + threadIdx.x) >> 6);
    int lane = (int)(threadIdx.x & 63);
    const float* src; unsigned short* dst; float* nrm; int row;
    if (gw < N_X) { src = x;   dst = xb; nrm = x2; row = gw; }
    else          { src = pat; dst = pb; nrm = p2; row = gw - N_X; }
    const float* r = src + (size_t)row * D_K;
    float4 v0 = *(const float4*)(r + lane * 4);        // cols [0,256)
    float4 v1 = *(const float4*)(r + 256 + lane * 4);  // cols [256,512)
    float s = v0.x * v0.x + v0.y * v0.y + v0.z * v0.z + v0.w * v0.w
            + v1.x * v1.x + v1.y * v1.y + v1.z * v1.z + v1.w * v1.w;
    ushort4 p0, p1;
    p0.x = f2bf(v0.x); p0.y = f2bf(v0.y); p0.z = f2bf(v0.z); p0.w = f2bf(v0.w);
    p1.x = f2bf(v1.x); p1.y = f2bf(v1.y); p1.z = f2bf(v1.z); p1.w = f2bf(v1.w);
    unsigned short* d = dst + (size_t)row * D_K;
    *(ushort4*)(d + lane * 4)       = p0;
    *(ushort4*)(d + 256 + lane * 4) = p1;
#pragma unroll
    for (int m = 32; m; m >>= 1) s += __shfl_xor(s, m);
    if (lane == 0) nrm[row] = s;
}

// ---------------------------------------------------------------------------
// Count targets -> inverse class sizes (single block).
// ---------------------------------------------------------------------------
__global__ void count_targets(const int* __restrict__ t, float* __restrict__ inv) {
    __shared__ int part[4];
    int c = 0;
    for (int m = (int)threadIdx.x; m < M_P; m += 256) c += t[m];
#pragma unroll
    for (int m = 32; m; m >>= 1) c += __shfl_xor(c, m);
    if ((threadIdx.x & 63) == 0) part[threadIdx.x >> 6] = c;
    __syncthreads();
    if (threadIdx.x == 0) {
        int n1 = part[0] + part[1] + part[2] + part[3];
        int n0 = M_P - n1;
        inv[0] = 1.0f / fmaxf((float)n0, 1.0f);
        inv[1] = 1.0f / fmaxf((float)n1, 1.0f);
    }
}

// ---------------------------------------------------------------------------
// Main fused kernel: bf16 MFMA GEMM (x @ p^T) + RBF epilogue + masked row
// reduction via per-row atomics. 4 waves, each owns a 64x64 output subtile.
// ---------------------------------------------------------------------------
__global__ __launch_bounds__(256) void pnn_main(
    const unsigned short* __restrict__ xb, const unsigned short* __restrict__ pb,
    const float* __restrict__ x2, const float* __restrict__ p2,
    const int* __restrict__ tgt, const float* __restrict__ invc,
    float* __restrict__ out) {
    __shared__ unsigned short As[2][BM][BK]; // 8 KiB per buffer; 32 KiB total LDS
    __shared__ unsigned short Bs[2][BN][BK];

    const int tid  = (int)threadIdx.x;
    const int wid  = tid >> 6;
    const int lane = tid & 63;
    const int wr   = wid >> 1;   // wave row 0..1 (64-row stripes of M)
    const int wc   = wid & 1;    // wave col 0..1 (64-col stripes of N)
    const int lr   = lane & 15;
    const int lg   = lane >> 4;
    const int tileM = (int)blockIdx.y * BM;
    const int tileN = (int)blockIdx.x * BN;

    f32x4 acc[4][4];
#pragma unroll
    for (int i = 0; i < 4; ++i)
#pragma unroll
        for (int j = 0; j < 4; ++j)
            acc[i][j] = (f32x4){0.f, 0.f, 0.f, 0.f};

    // Stage one 128xBK bf16 tile of A and B into LDS buffer `buf`.
    // Each wave stages 32 rows (2 issues of 16 rows); lane l covers
    // row (l>>2), elem-col (l&3)*8 within its 16-row chunk — exactly the
    // linear lane*16B LDS write order of global_load_lds (row-major, BK=32
    // bf16 = 64 B/row, 4 lanes/row).
    auto stage = [&](int buf, int k0) {
#pragma unroll
        for (int issue = 0; issue < 2; ++issue) {
            int rowBase = wid * 32 + issue * 16;
            int row = rowBase + (lane >> 2);
            int col = (lane & 3) * 8;
            gload_lds16(xb + (size_t)(tileM + row) * D_K + k0 + col,
                        &As[buf][rowBase][0]);
            gload_lds16(pb + (size_t)(tileN + row) * D_K + k0 + col,
                        &Bs[buf][rowBase][0]);
        }
    };

    stage(0, 0);
    __syncthreads(); // compiler emits vmcnt(0) drain before s_barrier: buf 0 ready

    for (int kt = 0; kt < NKT; ++kt) {
        int cur = kt & 1;
        if (kt + 1 < NKT) stage(cur ^ 1, (kt + 1) * BK);

        // A fragment: lane -> row lr, k = lg*8..lg*8+7 (bf16x8 contiguous).
        // B^T fragment: lane -> col lr (pattern row), same k split.
        bf16x8 a[4], b[4];
#pragma unroll
        for (int i = 0; i < 4; ++i)
            a[i] = *(const bf16x8*)&As[cur][wr * 64 + i * 16 + lr][lg * 8];
#pragma unroll
        for (int j = 0; j < 4; ++j)
            b[j] = *(const bf16x8*)&Bs[cur][wc * 64 + j * 16 + lr][lg * 8];
#pragma unroll
        for (int i = 0; i < 4; ++i)
#pragma unroll
            for (int j = 0; j < 4; ++j)
                acc[i][j] = __builtin_amdgcn_mfma_f32_16x16x32_bf16(
                    a[i], b[j], acc[i][j], 0, 0, 0);

        __syncthreads(); // joins waves + drains next-buffer staging
    }

    // Epilogue: k = exp(-max(x2 + p2 - 2c, 0)/2); masked row sums.
    // C/D layout (m89): col = lane&15 (N index), row = lg*4 + reg (M index).
    const float inv0 = invc[0], inv1 = invc[1];
    float p2c[4], w1[4];
#pragma unroll
    for (int j = 0; j < 4; ++j) {
        int m = tileN + wc * 64 + j * 16 + lr;
        p2c[j] = p2[m];
        w1[j] = (float)tgt[m]; // 1 if anomaly, 0 if normal
    }
#pragma unroll
    for (int i = 0; i < 4; ++i) {
#pragma unroll
        for (int r = 0; r < 4; ++r) {
            int n = tileM + wr * 64 + i * 16 + lg * 4 + r;
            float xn = x2[n];
            float s0 = 0.f, s1 = 0.f;
#pragma unroll
            for (int j = 0; j < 4; ++j) {
                float c = acc[i][j][r];
                float d = fmaxf(xn + p2c[j] - 2.0f * c, 0.0f);
                float k = __expf(-0.5f * d);
                float k1 = k * w1[j];
                s1 += k1;
                s0 += k - k1;
            }
            // reduce across the 16 lanes (lr = 0..15) holding this row's cols;
            // masks <16 keep lg bits intact, so each lg-group reduces its own row
#pragma unroll
            for (int msk = 1; msk < 16; msk <<= 1) {
                s0 += __shfl_xor(s0, msk);
                s1 += __shfl_xor(s1, msk);
            }
            if (lr == 0) {
                atomicAdd(&out[2 * n + 0], s0 * inv0);
                atomicAdd(&out[2 * n + 1], s1 * inv1);
            }
        }
    }
}

// ---------------------------------------------------------------------------
extern "C" void kernel_launch(void* const* d_in, const int* in_sizes, int n_in,
                              void* d_out, int out_size, void* d_ws, size_t ws_size,
                              hipStream_t stream) {
    const float* x   = (const float*)d_in[0];
    const float* pat = (const float*)d_in[1];
    const int*   tgt = (const int*)d_in[2];
    float* out = (float*)d_out;

    // Workspace layout (needs ~12.7 MiB):
    char* w = (char*)d_ws;
    unsigned short* xb = (unsigned short*)w;                              // 4 MiB
    unsigned short* pb = (unsigned short*)(w + (size_t)N_X * D_K * 2);    // 8 MiB
    float* x2   = (float*)(w + (size_t)(N_X + M_P) * D_K * 2);
    float* p2   = x2 + N_X;
    float* invc = p2 + M_P;

    hipMemsetAsync(d_out, 0, sizeof(float) * 2 * N_X, stream);
    prep_rows<<<(N_X + M_P) / 4, 256, 0, stream>>>(x, pat, xb, pb, x2, p2);
    count_targets<<<1, 256, 0, stream>>>(tgt, invc);
    dim3 grid(M_P / BN, N_X / BM); // 64 x 32 = 2048 blocks
    pnn_main<<<grid, 256, 0, stream>>>(xb, pb, x2, p2, tgt, invc, out);
}

// Round 4
// 178.342 us; speedup vs baseline: 1.2080x; 1.2080x over previous
//
#include <hip/hip_runtime.h>
#include <hip/hip_bf16.h>
#include <stdint.h>

// Problem constants (fixed by the reference setup_inputs).
#define N_X 4096
#define M_P 8192
#define D_K 512

// GEMM tile config — 256x256 tile, BK=32, 8 waves (2Mx4N), minimum-2-phase
// loop (T3 recipe): issue STAGE before ds_read+MFMA, one vmcnt+barrier/iter.
#define BM 256
#define BN 256
#define BK 32
#define NKT (D_K / BK) // 16 K-steps

typedef __attribute__((ext_vector_type(8))) short bf16x8; // 8 bf16 in 4 VGPRs
typedef __attribute__((ext_vector_type(4))) float f32x4;  // MFMA accumulator

// RNE float -> bf16 (bit math; NaN edge irrelevant for this data).
__device__ __forceinline__ unsigned short f2bf(float f) {
    union { float f; unsigned u; } c; c.f = f;
    unsigned u = c.u;
    return (unsigned short)((u + 0x7FFFu + ((u >> 16) & 1u)) >> 16);
}

// Async global->LDS, 16B per lane. LDS dest is wave-uniform base + lane*16.
__device__ __forceinline__ void gload_lds16(const void* g, void* l) {
    __builtin_amdgcn_global_load_lds(
        (const __attribute__((address_space(1))) void*)g,
        (__attribute__((address_space(3))) void*)l,
        16, 0, 0);
}

// ---------------------------------------------------------------------------
// Prep: one wave per row — f32 row norm + bf16 copy. Covers x (rows [0,N))
// then patterns (rows [N, N+M)) in a single launch.
// ---------------------------------------------------------------------------
__global__ void prep_rows(const float* __restrict__ x,
                          const float* __restrict__ pat,
                          unsigned short* __restrict__ xb,
                          unsigned short* __restrict__ pb,
                          float* __restrict__ x2, float* __restrict__ p2) {
    int gw   = (int)((blockIdx.x * blockDim.x + threadIdx.x) >> 6);
    int lane = (int)(threadIdx.x & 63);
    const float* src; unsigned short* dst; float* nrm; int row;
    if (gw < N_X) { src = x;   dst = xb; nrm = x2; row = gw; }
    else          { src = pat; dst = pb; nrm = p2; row = gw - N_X; }
    const float* r = src + (size_t)row * D_K;
    float4 v0 = *(const float4*)(r + lane * 4);        // cols [0,256)
    float4 v1 = *(const float4*)(r + 256 + lane * 4);  // cols [256,512)
    float s = v0.x * v0.x + v0.y * v0.y + v0.z * v0.z + v0.w * v0.w
            + v1.x * v1.x + v1.y * v1.y + v1.z * v1.z + v1.w * v1.w;
    ushort4 p0, p1;
    p0.x = f2bf(v0.x); p0.y = f2bf(v0.y); p0.z = f2bf(v0.z); p0.w = f2bf(v0.w);
    p1.x = f2bf(v1.x); p1.y = f2bf(v1.y); p1.z = f2bf(v1.z); p1.w = f2bf(v1.w);
    unsigned short* d = dst + (size_t)row * D_K;
    *(ushort4*)(d + lane * 4)       = p0;
    *(ushort4*)(d + 256 + lane * 4) = p1;
#pragma unroll
    for (int m = 32; m; m >>= 1) s += __shfl_xor(s, m);
    if (lane == 0) nrm[row] = s;
}

// ---------------------------------------------------------------------------
// Count targets -> inverse class sizes (single block, int4 loads).
// ---------------------------------------------------------------------------
__global__ void count_targets(const int* __restrict__ t, float* __restrict__ inv) {
    __shared__ int part[4];
    int c = 0;
    for (int m = (int)threadIdx.x; m < M_P / 4; m += 256) {
        int4 v = ((const int4*)t)[m];
        c += v.x + v.y + v.z + v.w;
    }
#pragma unroll
    for (int m = 32; m; m >>= 1) c += __shfl_xor(c, m);
    if ((threadIdx.x & 63) == 0) part[threadIdx.x >> 6] = c;
    __syncthreads();
    if (threadIdx.x == 0) {
        int n1 = part[0] + part[1] + part[2] + part[3];
        int n0 = M_P - n1;
        inv[0] = 1.0f / fmaxf((float)n0, 1.0f);
        inv[1] = 1.0f / fmaxf((float)n1, 1.0f);
    }
}

// ---------------------------------------------------------------------------
// Main fused kernel: bf16 MFMA GEMM (x @ p^T) + RBF epilogue + masked row
// reduction via per-row atomics. 8 waves, each owns a 128x64 output subtile.
// Minimum-2-phase pipelined loop with raw barriers (T3 recipe).
// ---------------------------------------------------------------------------
__global__ __launch_bounds__(512, 2) void pnn_main(
    const unsigned short* __restrict__ xb, const unsigned short* __restrict__ pb,
    const float* __restrict__ x2, const float* __restrict__ p2,
    const int* __restrict__ tgt, const float* __restrict__ invc,
    float* __restrict__ out) {
    __shared__ unsigned short As[2][BM][BK]; // 16 KiB per buffer
    __shared__ unsigned short Bs[2][BN][BK]; // total LDS = 64 KiB

    const int tid  = (int)threadIdx.x;
    const int wid  = tid >> 6;   // 0..7
    const int lane = tid & 63;
    const int wr   = wid >> 2;   // wave row 0..1 (128-row stripes of x)
    const int wc   = wid & 3;    // wave col 0..3 (64-col stripes of patterns)
    const int lr   = lane & 15;
    const int lg   = lane >> 4;

    // T1: XCD-chunked swizzle. 512 blocks -> 8 regions of 8x8 tiles; with
    // round-robin dispatch (wg%8 = XCD), each XCD works one region whose
    // working set is 2 MB of A + 2 MB of B = its 4 MB private L2. Bijective.
    const int wg  = (int)blockIdx.x;
    const int xcd = wg & 7, idx = wg >> 3;
    const int mr = xcd & 1, nr = xcd >> 1;
    const int tileM = (mr * 8 + (idx & 7)) * BM;   // x-tile    [0,16)*256
    const int tileN = (nr * 8 + (idx >> 3)) * BN;  // pat-tile  [0,32)*256

    f32x4 acc[8][4];
#pragma unroll
    for (int i = 0; i < 8; ++i)
#pragma unroll
        for (int j = 0; j < 4; ++j)
            acc[i][j] = (f32x4){0.f, 0.f, 0.f, 0.f};

    // Stage one 256xBK tile of A and B into buffer `buf`. Per issue, 512
    // threads cover 128 rows x 64 B (4 threads/row); wave w writes the 1-KiB
    // chunk at rows [i*128+w*16, +16) — LDS base is wave-uniform, global
    // address per-lane matches the linear lane*16B LDS write order.
    auto stage = [&](int buf, int k0) {
        const int rsub = wid * 16 + (lane >> 2); // 0..127 within issue
        const int col  = (lane & 3) * 8;         // bf16 col: 0/8/16/24
#pragma unroll
        for (int i = 0; i < 2; ++i) {
            gload_lds16(xb + (size_t)(tileM + i * 128 + rsub) * D_K + k0 + col,
                        &As[buf][i * 128 + wid * 16][0]);
            gload_lds16(pb + (size_t)(tileN + i * 128 + rsub) * D_K + k0 + col,
                        &Bs[buf][i * 128 + wid * 16][0]);
        }
    };

    stage(0, 0);
    asm volatile("s_waitcnt vmcnt(0)" ::: "memory");
    __builtin_amdgcn_s_barrier(); // buffer 0 ready for all waves

    for (int kt = 0; kt < NKT; ++kt) {
        const int cur = kt & 1;
        // Issue next tile's loads FIRST; their latency hides under the
        // ds_read+MFMA below. Overwrites buf read at kt-1 — safe: kt-1's
        // end-of-iter barrier followed lgkmcnt(0) on all waves.
        if (kt + 1 < NKT) stage(cur ^ 1, (kt + 1) * BK);

        // A fragment: lane -> x-row lr, k = lg*8..+8. B: lane -> pattern lr.
        bf16x8 a[8], b[4];
#pragma unroll
        for (int mi = 0; mi < 8; ++mi)
            a[mi] = *(const bf16x8*)&As[cur][wr * 128 + mi * 16 + lr][lg * 8];
#pragma unroll
        for (int nj = 0; nj < 4; ++nj)
            b[nj] = *(const bf16x8*)&Bs[cur][wc * 64 + nj * 16 + lr][lg * 8];

        __builtin_amdgcn_s_setprio(1);
#pragma unroll
        for (int mi = 0; mi < 8; ++mi)
#pragma unroll
            for (int nj = 0; nj < 4; ++nj)
                acc[mi][nj] = __builtin_amdgcn_mfma_f32_16x16x32_bf16(
                    a[mi], b[nj], acc[mi][nj], 0, 0, 0);
        __builtin_amdgcn_s_setprio(0);

        if (kt + 1 < NKT) {
            // lgkm(0): my ds_reads of buf[cur] retired (next iter overwrites);
            // vmcnt(0): my stage loads for buf[cur^1] landed; barrier: publish.
            asm volatile("s_waitcnt lgkmcnt(0)" ::: "memory");
            asm volatile("s_waitcnt vmcnt(0)" ::: "memory");
            __builtin_amdgcn_s_barrier();
        }
    }

    // Epilogue: k = exp(-max(x2 + p2 - 2c, 0)/2); masked row sums.
    // C/D layout (m89): col = lane&15 (pattern idx), row = lg*4 + reg (x idx).
    const float inv0 = invc[0], inv1 = invc[1];
    float p2c[4], w1[4];
#pragma unroll
    for (int nj = 0; nj < 4; ++nj) {
        int m = tileN + wc * 64 + nj * 16 + lr;
        p2c[nj] = p2[m];
        w1[nj] = (float)tgt[m]; // 1 if anomaly, 0 if normal
    }
#pragma unroll
    for (int mi = 0; mi < 8; ++mi) {
#pragma unroll
        for (int r = 0; r < 4; ++r) {
            int n = tileM + wr * 128 + mi * 16 + lg * 4 + r;
            float xn = x2[n];
            float s0 = 0.f, s1 = 0.f;
#pragma unroll
            for (int nj = 0; nj < 4; ++nj) {
                float c = acc[mi][nj][r];
                float d = fmaxf(xn + p2c[nj] - 2.0f * c, 0.0f);
                float k = __expf(-0.5f * d);
                float k1 = k * w1[nj];
                s1 += k1;
                s0 += k - k1;
            }
            // reduce across lr=0..15 (masks <16 keep lg intact: each lg-group
            // reduces its own x-row over this wave's 64 pattern columns)
#pragma unroll
            for (int msk = 1; msk < 16; msk <<= 1) {
                s0 += __shfl_xor(s0, msk);
                s1 += __shfl_xor(s1, msk);
            }
            if (lr == 0) {
                atomicAdd(&out[2 * n + 0], s0 * inv0);
                atomicAdd(&out[2 * n + 1], s1 * inv1);
            }
        }
    }
}

// ---------------------------------------------------------------------------
extern "C" void kernel_launch(void* const* d_in, const int* in_sizes, int n_in,
                              void* d_out, int out_size, void* d_ws, size_t ws_size,
                              hipStream_t stream) {
    const float* x   = (const float*)d_in[0];
    const float* pat = (const float*)d_in[1];
    const int*   tgt = (const int*)d_in[2];
    float* out = (float*)d_out;

    // Workspace layout (needs ~12.7 MiB):
    char* w = (char*)d_ws;
    unsigned short* xb = (unsigned short*)w;                              // 4 MiB
    unsigned short* pb = (unsigned short*)(w + (size_t)N_X * D_K * 2);    // 8 MiB
    float* x2   = (float*)(w + (size_t)(N_X + M_P) * D_K * 2);
    float* p2   = x2 + N_X;
    float* invc = p2 + M_P;

    hipMemsetAsync(d_out, 0, sizeof(float) * 2 * N_X, stream);
    prep_rows<<<(N_X + M_P) / 4, 256, 0, stream>>>(x, pat, xb, pb, x2, p2);
    count_targets<<<1, 256, 0, stream>>>(tgt, invc);
    // 1-D grid of 512 blocks; tile coords derived via XCD-chunked swizzle.
    pnn_main<<<(N_X / BM) * (M_P / BN), 512, 0, stream>>>(
        xb, pb, x2, p2, tgt, invc, out);
}

// Round 9
// 176.231 us; speedup vs baseline: 1.2225x; 1.0120x over previous
//
#include <hip/hip_runtime.h>
#include <hip/hip_bf16.h>
#include <stdint.h>

// Problem constants (fixed by the reference setup_inputs).
#define N_X 4096
#define M_P 8192
#define D_K 512

// 256x256 tile, BK=32, 8 waves (2Mx4N). Triple-buffered LDS, prefetch
// depth 2, counted vmcnt(8) (T4): the tile a barrier publishes was issued
// two iterations earlier -> L2/HBM latency hidden. XOR-swizzled LDS
// (linear dest + pre-swizzled global source + swizzled read, rule #21).
#define BM 256
#define BN 256
#define BK 32
#define NKT (D_K / BK) // 16 K-tiles

typedef __attribute__((ext_vector_type(8))) short bf16x8; // 8 bf16 in 4 VGPRs
typedef __attribute__((ext_vector_type(4))) float f32x4;  // MFMA accumulator

// RNE float -> bf16 (bit math; NaN edge irrelevant for this data).
__device__ __forceinline__ unsigned short f2bf(float f) {
    union { float f; unsigned u; } c; c.f = f;
    unsigned u = c.u;
    return (unsigned short)((u + 0x7FFFu + ((u >> 16) & 1u)) >> 16);
}

// Async global->LDS, 16B per lane. LDS dest is wave-uniform base + lane*16.
__device__ __forceinline__ void gload_lds16(const void* g, void* l) {
    __builtin_amdgcn_global_load_lds(
        (const __attribute__((address_space(1))) void*)g,
        (__attribute__((address_space(3))) void*)l,
        16, 0, 0);
}

// ---------------------------------------------------------------------------
// Prep: one wave per row — f32 row norm + bf16 copy. Covers x (rows [0,N))
// then patterns (rows [N, N+M)) in a single launch.
// ---------------------------------------------------------------------------
__global__ void prep_rows(const float* __restrict__ x,
                          const float* __restrict__ pat,
                          unsigned short* __restrict__ xb,
                          unsigned short* __restrict__ pb,
                          float* __restrict__ x2, float* __restrict__ p2) {
    int gw   = (int)((blockIdx.x * blockDim.x + threadIdx.x) >> 6);
    int lane = (int)(threadIdx.x & 63);
    const float* src; unsigned short* dst; float* nrm; int row;
    if (gw < N_X) { src = x;   dst = xb; nrm = x2; row = gw; }
    else          { src = pat; dst = pb; nrm = p2; row = gw - N_X; }
    const float* r = src + (size_t)row * D_K;
    float4 v0 = *(const float4*)(r + lane * 4);        // cols [0,256)
    float4 v1 = *(const float4*)(r + 256 + lane * 4);  // cols [256,512)
    float s = v0.x * v0.x + v0.y * v0.y + v0.z * v0.z + v0.w * v0.w
            + v1.x * v1.x + v1.y * v1.y + v1.z * v1.z + v1.w * v1.w;
    ushort4 p0, p1;
    p0.x = f2bf(v0.x); p0.y = f2bf(v0.y); p0.z = f2bf(v0.z); p0.w = f2bf(v0.w);
    p1.x = f2bf(v1.x); p1.y = f2bf(v1.y); p1.z = f2bf(v1.z); p1.w = f2bf(v1.w);
    unsigned short* d = dst + (size_t)row * D_K;
    *(ushort4*)(d + lane * 4)       = p0;
    *(ushort4*)(d + 256 + lane * 4) = p1;
#pragma unroll
    for (int m = 32; m; m >>= 1) s += __shfl_xor(s, m);
    if (lane == 0) nrm[row] = s;
}

// ---------------------------------------------------------------------------
// Count targets -> inverse class sizes (single block, int4 loads).
// ---------------------------------------------------------------------------
__global__ void count_targets(const int* __restrict__ t, float* __restrict__ inv) {
    __shared__ int part[4];
    int c = 0;
    for (int m = (int)threadIdx.x; m < M_P / 4; m += 256) {
        int4 v = ((const int4*)t)[m];
        c += v.x + v.y + v.z + v.w;
    }
#pragma unroll
    for (int m = 32; m; m >>= 1) c += __shfl_xor(c, m);
    if ((threadIdx.x & 63) == 0) part[threadIdx.x >> 6] = c;
    __syncthreads();
    if (threadIdx.x == 0) {
        int n1 = part[0] + part[1] + part[2] + part[3];
        int n0 = M_P - n1;
        inv[0] = 1.0f / fmaxf((float)n0, 1.0f);
        inv[1] = 1.0f / fmaxf((float)n1, 1.0f);
    }
}

// ---------------------------------------------------------------------------
// Main fused kernel: bf16 MFMA GEMM (x @ p^T) + RBF epilogue + masked row
// reduction. 8 waves, each owns a 128x64 output subtile. Triple-buffered
// pipeline, prefetch depth 2, counted vmcnt.
// ---------------------------------------------------------------------------
__global__ __launch_bounds__(512, 2) void pnn_main(
    const unsigned short* __restrict__ xb, const unsigned short* __restrict__ pb,
    const float* __restrict__ x2, const float* __restrict__ p2,
    const int* __restrict__ tgt, const float* __restrict__ invc,
    float* __restrict__ out) {
    __shared__ unsigned short As[3][BM][BK]; // 3 x 16 KiB
    __shared__ unsigned short Bs[3][BN][BK]; // total LDS = 96 KiB -> 1 block/CU

    const int tid  = (int)threadIdx.x;
    const int wid  = tid >> 6;   // 0..7
    const int lane = tid & 63;
    const int wr   = wid >> 2;   // wave row 0..1 (128-row stripes of x)
    const int wc   = wid & 3;    // wave col 0..3 (64-col stripes of patterns)
    const int lr   = lane & 15;
    const int lg   = lane >> 4;

    // T1: XCD-chunked swizzle. 512 blocks -> 8 regions of 8x8 tiles (each
    // XCD's region working set ~3 MB < its 4 MB L2). Bijective.
    const int wg  = (int)blockIdx.x;
    const int xcd = wg & 7, idx = wg >> 3;
    const int mr = xcd & 1, nr = xcd >> 1;
    const int tileM = (mr * 8 + (idx & 7)) * BM;   // x-tile    [0,16)*256
    const int tileN = (nr * 8 + (idx >> 3)) * BN;  // pat-tile  [0,32)*256

    f32x4 acc[8][4];
#pragma unroll
    for (int i = 0; i < 8; ++i)
#pragma unroll
        for (int j = 0; j < 4; ++j)
            acc[i][j] = (f32x4){0.f, 0.f, 0.f, 0.f};

    // --- LDS XOR swizzle (derived for [256][32] bf16, 64 B rows) ---------
    // Logical (row R, col-elem 8q) lives at physical col-elem 8*(q ^ ((R>>1)&3)).
    // Read banks: 16 lanes (lr) spread over 8 distinct 4-bank sets = 2-way (free).
    // global_load_lds writes linearly -> pre-swizzle the GLOBAL source col.
    // Writer thread: phys row = wid*16 + (lane>>2), phys col-elem 8*(lane&3),
    // so it must fetch global col-elem 8*((lane&3) ^ ((lane>>3)&3)).
    auto stage = [&](int b, int k0) {
        const int r  = wid * 16 + (lane >> 2);                 // 0..127
        const int ce = (((lane & 3) ^ ((lane >> 3) & 3)) * 8); // swizzled src col
#pragma unroll
        for (int i = 0; i < 2; ++i) {
            gload_lds16(xb + (size_t)(tileM + i * 128 + r) * D_K + k0 + ce,
                        &As[b][i * 128 + wid * 16][0]);
            gload_lds16(pb + (size_t)(tileN + i * 128 + r) * D_K + k0 + ce,
                        &Bs[b][i * 128 + wid * 16][0]);
        }
    };

    // Prologue: stage tiles 0 and 1 (4 loads/thread each).
    stage(0, 0 * BK);
    stage(1, 1 * BK);

    // Swizzled read col for fragments: logical col 8*lg -> phys 8*(lg^((lr>>1)&3)).
    const int asw = (lg ^ ((lr >> 1) & 3)) * 8;

#pragma unroll
    for (int kt = 0; kt < NKT; ++kt) {
        const int b = kt % 3;
        // Prefetch depth 2: stage tile kt+2 into buffer (kt+2)%3 == (kt-1)%3,
        // whose readers (iter kt-1) drained lgkm and joined the closing
        // barrier before we got here. No race.
        if (kt + 2 < NKT) stage((kt + 2) % 3, (kt + 2) * BK);

        // Counted wait (T4): retire only tile kt's 4 loads; leave tiles
        // kt+1/kt+2 (up to 8 loads) in flight across the barrier.
        if (kt + 2 < NKT)      asm volatile("s_waitcnt vmcnt(8)" ::: "memory");
        else if (kt + 1 < NKT) asm volatile("s_waitcnt vmcnt(4)" ::: "memory");
        else                   asm volatile("s_waitcnt vmcnt(0)" ::: "memory");
        __builtin_amdgcn_s_barrier(); // all waves' tile-kt chunks are in LDS

        // A frag: x-row lr, k-slice lg*8..+8 (swizzled). B frag: pattern lr.
        bf16x8 a[8], bfr[4];
#pragma unroll
        for (int mi = 0; mi < 8; ++mi)
            a[mi] = *(const bf16x8*)&As[b][wr * 128 + mi * 16 + lr][asw];
#pragma unroll
        for (int nj = 0; nj < 4; ++nj)
            bfr[nj] = *(const bf16x8*)&Bs[b][wc * 64 + nj * 16 + lr][asw];

        __builtin_amdgcn_s_setprio(1);
#pragma unroll
        for (int mi = 0; mi < 8; ++mi)
#pragma unroll
            for (int nj = 0; nj < 4; ++nj)
                acc[mi][nj] = __builtin_amdgcn_mfma_f32_16x16x32_bf16(
                    a[mi], bfr[nj], acc[mi][nj], 0, 0, 0);
        __builtin_amdgcn_s_setprio(0);

        // Closing fence only while a future stage will overwrite buffer
        // (kt+3)%3 == b: my ds_reads must be done (lgkm) and all waves
        // joined before anyone issues that DMA.
        if (kt + 3 < NKT) {
            asm volatile("s_waitcnt lgkmcnt(0)" ::: "memory");
            __builtin_amdgcn_s_barrier();
        }
    }

    // Epilogue: k = exp(-max(x2 + p2 - 2c, 0)/2); masked row sums.
    // C/D layout (m89): col = lane&15 (pattern idx), row = lg*4 + reg (x idx).
    const float inv0 = invc[0], inv1 = invc[1];
    float p2c[4], w1[4];
#pragma unroll
    for (int nj = 0; nj < 4; ++nj) {
        int m = tileN + wc * 64 + nj * 16 + lr;
        p2c[nj] = p2[m];
        w1[nj] = (float)tgt[m]; // 1 if anomaly, 0 if normal
    }
#pragma unroll
    for (int mi = 0; mi < 8; ++mi) {
#pragma unroll
        for (int r = 0; r < 4; ++r) {
            int n = tileM + wr * 128 + mi * 16 + lg * 4 + r;
            float xn = x2[n];
            float s0 = 0.f, s1 = 0.f;
#pragma unroll
            for (int nj = 0; nj < 4; ++nj) {
                float c = acc[mi][nj][r];
                float d = fmaxf(xn + p2c[nj] - 2.0f * c, 0.0f);
                float k = __expf(-0.5f * d);
                float k1 = k * w1[nj];
                s1 += k1;
                s0 += k - k1;
            }
            // reduce across lr=0..15 (masks <16 keep lg intact: each lg-group
            // reduces its own x-row over this wave's 64 pattern columns)
#pragma unroll
            for (int msk = 1; msk < 16; msk <<= 1) {
                s0 += __shfl_xor(s0, msk);
                s1 += __shfl_xor(s1, msk);
            }
            if (lr == 0) {
                atomicAdd(&out[2 * n + 0], s0 * inv0);
                atomicAdd(&out[2 * n + 1], s1 * inv1);
            }
        }
    }
}

// ---------------------------------------------------------------------------
extern "C" void kernel_launch(void* const* d_in, const int* in_sizes, int n_in,
                              void* d_out, int out_size, void* d_ws, size_t ws_size,
                              hipStream_t stream) {
    const float* x   = (const float*)d_in[0];
    const float* pat = (const float*)d_in[1];
    const int*   tgt = (const int*)d_in[2];
    float* out = (float*)d_out;

    // Workspace layout (needs ~12.7 MiB):
    char* w = (char*)d_ws;
    unsigned short* xb = (unsigned short*)w;                              // 4 MiB
    unsigned short* pb = (unsigned short*)(w + (size_t)N_X * D_K * 2);    // 8 MiB
    float* x2   = (float*)(w + (size_t)(N_X + M_P) * D_K * 2);
    float* p2   = x2 + N_X;
    float* invc = p2 + M_P;

    hipMemsetAsync(d_out, 0, sizeof(float) * 2 * N_X, stream);
    prep_rows<<<(N_X + M_P) / 4, 256, 0, stream>>>(x, pat, xb, pb, x2, p2);
    count_targets<<<1, 256, 0, stream>>>(tgt, invc);
    // 1-D grid of 512 blocks; tile coords derived via XCD-chunked swizzle.
    pnn_main<<<(N_X / BM) * (M_P / BN), 512, 0, stream>>>(
        xb, pb, x2, p2, tgt, invc, out);
}

// Round 14
// 163.223 us; speedup vs baseline: 1.3199x; 1.0797x over previous
//
#include <hip/hip_runtime.h>
#include <hip/hip_bf16.h>
#include <stdint.h>

// Problem constants (fixed by the reference setup_inputs).
#define N_X 4096
#define M_P 8192
#define D_K 512

// 256x128 tile, BK=32, 8 waves (4Mx2N), per-wave 64x64 output (acc[4][4]).
// Triple-buffered LDS (72 KiB) + counted vmcnt (T4) + XOR swizzle; sized so
// TWO blocks co-reside per CU (LDS 2x72<=160, regs <=128/thread @ 16 waves)
// -> cross-block TLP hides stage/barrier/epilogue latency (m114 mechanism).
#define BM 256
#define BN 128
#define BK 32
#define NKT (D_K / BK) // 16 K-tiles

typedef __attribute__((ext_vector_type(8))) short bf16x8; // 8 bf16 in 4 VGPRs
typedef __attribute__((ext_vector_type(4))) float f32x4;  // MFMA accumulator

// RNE float -> bf16 (bit math; NaN edge irrelevant for this data).
__device__ __forceinline__ unsigned short f2bf(float f) {
    union { float f; unsigned u; } c; c.f = f;
    unsigned u = c.u;
    return (unsigned short)((u + 0x7FFFu + ((u >> 16) & 1u)) >> 16);
}

// Async global->LDS, 16B per lane. LDS dest is wave-uniform base + lane*16.
__device__ __forceinline__ void gload_lds16(const void* g, void* l) {
    __builtin_amdgcn_global_load_lds(
        (const __attribute__((address_space(1))) void*)g,
        (__attribute__((address_space(3))) void*)l,
        16, 0, 0);
}

// ---------------------------------------------------------------------------
// Prep: one wave per row — f32 row norm + bf16 copy. Covers x (rows [0,N))
// then patterns (rows [N, N+M)) in a single launch.
// ---------------------------------------------------------------------------
__global__ void prep_rows(const float* __restrict__ x,
                          const float* __restrict__ pat,
                          unsigned short* __restrict__ xb,
                          unsigned short* __restrict__ pb,
                          float* __restrict__ x2, float* __restrict__ p2) {
    int gw   = (int)((blockIdx.x * blockDim.x + threadIdx.x) >> 6);
    int lane = (int)(threadIdx.x & 63);
    const float* src; unsigned short* dst; float* nrm; int row;
    if (gw < N_X) { src = x;   dst = xb; nrm = x2; row = gw; }
    else          { src = pat; dst = pb; nrm = p2; row = gw - N_X; }
    const float* r = src + (size_t)row * D_K;
    float4 v0 = *(const float4*)(r + lane * 4);        // cols [0,256)
    float4 v1 = *(const float4*)(r + 256 + lane * 4);  // cols [256,512)
    float s = v0.x * v0.x + v0.y * v0.y + v0.z * v0.z + v0.w * v0.w
            + v1.x * v1.x + v1.y * v1.y + v1.z * v1.z + v1.w * v1.w;
    ushort4 p0, p1;
    p0.x = f2bf(v0.x); p0.y = f2bf(v0.y); p0.z = f2bf(v0.z); p0.w = f2bf(v0.w);
    p1.x = f2bf(v1.x); p1.y = f2bf(v1.y); p1.z = f2bf(v1.z); p1.w = f2bf(v1.w);
    unsigned short* d = dst + (size_t)row * D_K;
    *(ushort4*)(d + lane * 4)       = p0;
    *(ushort4*)(d + 256 + lane * 4) = p1;
#pragma unroll
    for (int m = 32; m; m >>= 1) s += __shfl_xor(s, m);
    if (lane == 0) nrm[row] = s;
}

// ---------------------------------------------------------------------------
// Count targets -> inverse class sizes (single block, int4 loads).
// ---------------------------------------------------------------------------
__global__ void count_targets(const int* __restrict__ t, float* __restrict__ inv) {
    __shared__ int part[4];
    int c = 0;
    for (int m = (int)threadIdx.x; m < M_P / 4; m += 256) {
        int4 v = ((const int4*)t)[m];
        c += v.x + v.y + v.z + v.w;
    }
#pragma unroll
    for (int m = 32; m; m >>= 1) c += __shfl_xor(c, m);
    if ((threadIdx.x & 63) == 0) part[threadIdx.x >> 6] = c;
    __syncthreads();
    if (threadIdx.x == 0) {
        int n1 = part[0] + part[1] + part[2] + part[3];
        int n0 = M_P - n1;
        inv[0] = 1.0f / fmaxf((float)n0, 1.0f);
        inv[1] = 1.0f / fmaxf((float)n1, 1.0f);
    }
}

// ---------------------------------------------------------------------------
// Main fused kernel: bf16 MFMA GEMM (x @ p^T) + RBF epilogue + masked row
// reduction via LDS transpose + one atomic per (row,class).
// ---------------------------------------------------------------------------
__global__ __launch_bounds__(512, 4) void pnn_main(
    const unsigned short* __restrict__ xb, const unsigned short* __restrict__ pb,
    const float* __restrict__ x2, const float* __restrict__ p2,
    const int* __restrict__ tgt, const float* __restrict__ invc,
    float* __restrict__ out) {
    // 72 KiB staging LDS, overlaid with the 68 KiB epilogue partial buffer.
    // part's l-dim padded 16->17: row stride 68 dwords => reduce-read bank =
    // (rl*4 + w*2 + l*2 + cls)%32 -> 16 banks/64 lanes = 4-way (near-free).
    // Unpadded (stride 64) collapsed to 2 banks = 32-way conflict.
    __shared__ union SMem {
        struct { unsigned short As[3][BM][BK]; unsigned short Bs[3][BN][BK]; } g;
        float part[BM][2][17][2]; // [row][waveColN][lr(+pad)][class]
    } sm;

    const int tid  = (int)threadIdx.x;
    const int wid  = tid >> 6;   // 0..7
    const int lane = tid & 63;
    const int wrM  = wid >> 1;   // wave row 0..3 (64-row stripes of x)
    const int wcN  = wid & 1;    // wave col 0..1 (64-col stripes of patterns)
    const int lr   = lane & 15;
    const int lg   = lane >> 4;

    // T1: 1024 blocks -> xcd = wg&7 owns an N-slab of 8 tile-cols (1 MB of
    // patterns, fits its private L2); A (4 MB total) is shared via L3.
    const int wg  = (int)blockIdx.x;
    const int xcd = wg & 7, idx = wg >> 3;           // idx in [0,128)
    const int tileM = (idx >> 3) * BM;               // [0,16)*256
    const int tileN = (xcd * 8 + (idx & 7)) * BN;    // [0,64)*128

    f32x4 acc[4][4];
#pragma unroll
    for (int i = 0; i < 4; ++i)
#pragma unroll
        for (int j = 0; j < 4; ++j)
            acc[i][j] = (f32x4){0.f, 0.f, 0.f, 0.f};

    // --- LDS XOR swizzle (verified R9: conflicts 3.1M -> 0) --------------
    // Logical (row R, col-elem 8q) -> physical col-elem 8*(q ^ ((R>>1)&3)).
    // Linear DMA dest + pre-swizzled GLOBAL source col + swizzled read.
    // Writer: phys row = wid*16 + (lane>>2) => (R>>1)&3 == (lane>>3)&3.
    auto stage = [&](int b, int k0) {
        const int r  = wid * 16 + (lane >> 2);                 // 0..127
        const int ce = (((lane & 3) ^ ((lane >> 3) & 3)) * 8); // swizzled src col
        // A tile: 256 rows = 2 issues of 128 rows.
#pragma unroll
        for (int i = 0; i < 2; ++i)
            gload_lds16(xb + (size_t)(tileM + i * 128 + r) * D_K + k0 + ce,
                        &sm.g.As[b][i * 128 + wid * 16][0]);
        // B tile: 128 rows = 1 issue.
        gload_lds16(pb + (size_t)(tileN + r) * D_K + k0 + ce,
                    &sm.g.Bs[b][wid * 16][0]);
    };

    // Prologue: stage tiles 0 and 1 (3 loads/thread each -> vmcnt 6).
    stage(0, 0 * BK);
    stage(1, 1 * BK);

    // Swizzled read col: logical col 8*lg -> phys 8*(lg ^ ((lr>>1)&3)).
    const int asw = (lg ^ ((lr >> 1) & 3)) * 8;

#pragma unroll
    for (int kt = 0; kt < NKT; ++kt) {
        const int b = kt % 3;
        // Depth-2 prefetch into buffer (kt+2)%3 == (kt-1)%3 (readers drained
        // at iter kt-1's closing fence).
        if (kt + 2 < NKT) stage((kt + 2) % 3, (kt + 2) * BK);

        // Counted wait (T4): retire only tile kt's 3 loads; tiles kt+1/kt+2
        // (up to 6 loads) stay in flight across the barrier.
        if (kt + 2 < NKT)      asm volatile("s_waitcnt vmcnt(6)" ::: "memory");
        else if (kt + 1 < NKT) asm volatile("s_waitcnt vmcnt(3)" ::: "memory");
        else                   asm volatile("s_waitcnt vmcnt(0)" ::: "memory");
        __builtin_amdgcn_s_barrier(); // all waves' tile-kt chunks are in LDS

        bf16x8 a[4], bfr[4];
#pragma unroll
        for (int mi = 0; mi < 4; ++mi)
            a[mi] = *(const bf16x8*)&sm.g.As[b][wrM * 64 + mi * 16 + lr][asw];
#pragma unroll
        for (int nj = 0; nj < 4; ++nj)
            bfr[nj] = *(const bf16x8*)&sm.g.Bs[b][wcN * 64 + nj * 16 + lr][asw];

        __builtin_amdgcn_s_setprio(1);
#pragma unroll
        for (int mi = 0; mi < 4; ++mi)
#pragma unroll
            for (int nj = 0; nj < 4; ++nj)
                acc[mi][nj] = __builtin_amdgcn_mfma_f32_16x16x32_bf16(
                    a[mi], bfr[nj], acc[mi][nj], 0, 0, 0);
        __builtin_amdgcn_s_setprio(0);

        // Closing fence while a future stage will overwrite buffer b.
        if (kt + 3 < NKT) {
            asm volatile("s_waitcnt lgkmcnt(0)" ::: "memory");
            __builtin_amdgcn_s_barrier();
        }
    }

    // ---- Epilogue ------------------------------------------------------
    // k = exp(-max(x2 + p2 - 2c, 0)/2); masked sums over this block's 128
    // pattern cols. C/D layout (m89): col = lr (pattern), row = lg*4+reg (x).
    const float inv0 = invc[0], inv1 = invc[1];
    float p2c[4], w1[4];
#pragma unroll
    for (int nj = 0; nj < 4; ++nj) {
        int m = tileN + wcN * 64 + nj * 16 + lr;
        p2c[nj] = p2[m];
        w1[nj] = (float)tgt[m]; // 1 if anomaly, 0 if normal
    }

    // All waves done with their frag reads; join before overlaying LDS.
    asm volatile("s_waitcnt lgkmcnt(0)" ::: "memory");
    __builtin_amdgcn_s_barrier();

#pragma unroll
    for (int mi = 0; mi < 4; ++mi) {
#pragma unroll
        for (int r = 0; r < 4; ++r) {
            int rl = wrM * 64 + mi * 16 + lg * 4 + r; // local row [0,256)
            float xn = x2[tileM + rl];
            float s0 = 0.f, s1 = 0.f;
#pragma unroll
            for (int nj = 0; nj < 4; ++nj) {
                float c = acc[mi][nj][r];
                float d = fmaxf(xn + p2c[nj] - 2.0f * c, 0.0f);
                float k = __expf(-0.5f * d);
                float k1 = k * w1[nj];
                s1 += k1;
                s0 += k - k1;
            }
            // per-thread partial over its 4 cols -> LDS (disjoint slots)
            sm.part[rl][wcN][lr][0] = s0;
            sm.part[rl][wcN][lr][1] = s1;
        }
    }
    __syncthreads();

    // Reduce 32 partials per (row,class); one atomic per (row,class).
    {
        int rl  = tid >> 1;        // [0,256)
        int cls = tid & 1;
        float s = 0.f;
#pragma unroll
        for (int w = 0; w < 2; ++w)
#pragma unroll
            for (int l = 0; l < 16; ++l)
                s += sm.part[rl][w][l][cls];
        atomicAdd(&out[2 * (tileM + rl) + cls], s * (cls ? inv1 : inv0));
    }
}

// ---------------------------------------------------------------------------
extern "C" void kernel_launch(void* const* d_in, const int* in_sizes, int n_in,
                              void* d_out, int out_size, void* d_ws, size_t ws_size,
                              hipStream_t stream) {
    const float* x   = (const float*)d_in[0];
    const float* pat = (const float*)d_in[1];
    const int*   tgt = (const int*)d_in[2];
    float* out = (float*)d_out;

    // Workspace layout (needs ~12.7 MiB):
    char* w = (char*)d_ws;
    unsigned short* xb = (unsigned short*)w;                              // 4 MiB
    unsigned short* pb = (unsigned short*)(w + (size_t)N_X * D_K * 2);    // 8 MiB
    float* x2   = (float*)(w + (size_t)(N_X + M_P) * D_K * 2);
    float* p2   = x2 + N_X;
    float* invc = p2 + M_P;

    hipMemsetAsync(d_out, 0, sizeof(float) * 2 * N_X, stream);
    prep_rows<<<(N_X + M_P) / 4, 256, 0, stream>>>(x, pat, xb, pb, x2, p2);
    count_targets<<<1, 256, 0, stream>>>(tgt, invc);
    // 1024 blocks (16 M-tiles x 64 N-tiles), XCD-slab swizzled.
    pnn_main<<<(N_X / BM) * (M_P / BN), 512, 0, stream>>>(
        xb, pb, x2, p2, tgt, invc, out);
}